// Round 1
// 3448.184 us; speedup vs baseline: 1.4721x; 1.4721x over previous
//
#include <hip/hip_runtime.h>
#include <hip/hip_bf16.h>
#include <math.h>

#define BB 64
#define NPIX 196
#define ENCD 2048
#define DECD 512
#define VOCAB_N 10000
#define MAXLEN 52
#define TT 51
#define NOUT 12608   // cols: [0,10048) W_fc(10000+48 pad) | [10048,12096) W_fbeta | [12096,12608) W_dec_att

// Output layout (floats): preds | captions | declens | alphas
#define PRED_SZ   (BB * TT * VOCAB_N)
#define CAPS_SZ   (BB * MAXLEN)
#define LENS_SZ   (BB)
#define ALPHAS_OFF (PRED_SZ + CAPS_SZ + LENS_SZ)

typedef __attribute__((ext_vector_type(8))) short short8;
typedef __attribute__((ext_vector_type(4))) short short4v;
typedef __attribute__((ext_vector_type(4))) float f32x4;

__device__ __forceinline__ float fsigm(float x) {
    return 1.0f / (1.0f + __expf(-x));
}
__device__ __forceinline__ float ftanh(float x) {
    x = fminf(fmaxf(x, -15.0f), 15.0f);
    float e = __expf(2.0f * x);
    return (e - 1.0f) / (e + 1.0f);
}
__device__ __forceinline__ float bf2f(unsigned short u) {
    union { unsigned int i; float f; } v;
    v.i = ((unsigned int)u) << 16;
    return v.f;
}
__device__ __forceinline__ unsigned short f2bf(float f) {
    union { float f; unsigned int i; } v;
    v.f = f;
    unsigned int r = v.i + 0x7FFFu + ((v.i >> 16) & 1u);
    return (unsigned short)(r >> 16);
}

// ---------------------------------------------------------------------------
// Generic MFMA GEMM: C[M,N] = act(A[M,K_slice] @ Wp + bias) (row-masked).
// A row-major bf16 (lda elems). Wp packed: Wp[kb][n][kk], kk=0..31.
// Block = 4 waves; wave w covers rows m0+16w..+15, cols n0..n0+63 (4 frags).
// blockIdx.z = K-slice (nkb k-blocks each); multi-slice writes partials.
// ---------------------------------------------------------------------------
__global__ __launch_bounds__(256) void gemm_mfma(
    const unsigned short* __restrict__ A, int lda,
    const unsigned short* __restrict__ Wp, int Npad,
    int nkb, long slice_stride,
    float* __restrict__ C, unsigned short* __restrict__ C16, long ldc,
    const float* __restrict__ bias, int N, int act,
    const int* __restrict__ caplen, int t)
{
    const int n0 = blockIdx.x * 64;
    const int m0 = blockIdx.y * 64;
    const int kz = blockIdx.z;
    A  += (size_t)kz * nkb * 32;
    Wp += (size_t)kz * nkb * Npad * 32;
    if (C) C += (size_t)kz * slice_stride;

    const int w  = threadIdx.x >> 6;
    const int l  = threadIdx.x & 63;
    const int lr = l & 15;   // A-row / B-col / D-col within 16-tile
    const int q  = l >> 4;   // k sub-block: k = q*8 + j

    const unsigned short* ap = A + (size_t)(m0 + 16 * w + lr) * lda + q * 8;
    const unsigned short* bp = Wp + (size_t)(n0 + lr) * 32 + q * 8;
    const size_t bstep = (size_t)Npad * 32;

    f32x4 acc[4];
#pragma unroll
    for (int i = 0; i < 4; ++i) acc[i] = (f32x4){0.f, 0.f, 0.f, 0.f};

    short8 a  = *(const short8*)ap;
    short8 b0 = *(const short8*)(bp);
    short8 b1 = *(const short8*)(bp + 512);
    short8 b2 = *(const short8*)(bp + 1024);
    short8 b3 = *(const short8*)(bp + 1536);

    for (int kb = 0; kb < nkb; ++kb) {
        const size_t nxt = (kb + 1 < nkb) ? 1 : 0;
        const unsigned short* apn = ap + nxt * 32;
        const unsigned short* bpn = bp + nxt * bstep;
        short8 an  = *(const short8*)apn;
        short8 bn0 = *(const short8*)(bpn);
        short8 bn1 = *(const short8*)(bpn + 512);
        short8 bn2 = *(const short8*)(bpn + 1024);
        short8 bn3 = *(const short8*)(bpn + 1536);
        acc[0] = __builtin_amdgcn_mfma_f32_16x16x32_bf16(a, b0, acc[0], 0, 0, 0);
        acc[1] = __builtin_amdgcn_mfma_f32_16x16x32_bf16(a, b1, acc[1], 0, 0, 0);
        acc[2] = __builtin_amdgcn_mfma_f32_16x16x32_bf16(a, b2, acc[2], 0, 0, 0);
        acc[3] = __builtin_amdgcn_mfma_f32_16x16x32_bf16(a, b3, acc[3], 0, 0, 0);
        a = an; b0 = bn0; b1 = bn1; b2 = bn2; b3 = bn3;
        ap = apn; bp = bpn;
    }

    const int r0 = q * 4;
#pragma unroll
    for (int cf = 0; cf < 4; ++cf) {
        int col = n0 + cf * 16 + lr;
        if (col >= N) continue;
        float bv = bias ? bias[col] : 0.f;
#pragma unroll
        for (int r = 0; r < 4; ++r) {
            int row = m0 + 16 * w + r0 + r;
            float v = acc[cf][r] + bv;
            if (act == 1 || (act == 2 && col < 2048)) v = fsigm(v);
            if (caplen) v *= (t < caplen[row] - 1) ? 1.f : 0.f;
            if (C16) C16[(size_t)row * ldc + col] = f2bf(v);
            else     C [(size_t)row * ldc + col] = v;
        }
    }
}

// ---------------------------------------------------------------------------
// Fused output GEMM: given h (64x512 bf16 in xcat, lda=3072) compute
//   cols [0,10000):      preds(t) = (h@W_fc + b_fc) * mask   -> out
//   cols [10048,12096):  gate     = sigmoid(h@W_fbeta + b)   -> gadec[:, 0:2048]
//   cols [12096,12608):  adec     = h@W_dec_att + b          -> gadec[:, 2048:2560]
// nbase shifts the column window (setup pass covers only gate|adec: nbase=157).
// ---------------------------------------------------------------------------
__global__ __launch_bounds__(256) void outgemm_kernel(
    const unsigned short* __restrict__ h16,
    const unsigned short* __restrict__ Wp,
    const float* __restrict__ bias,
    const int* __restrict__ caplen, int t,
    float* __restrict__ preds, long ldc,
    float* __restrict__ gadec, int nbase)
{
    const int n0 = (nbase + blockIdx.x) * 64;
    const int w  = threadIdx.x >> 6;
    const int l  = threadIdx.x & 63;
    const int lr = l & 15;
    const int q  = l >> 4;

    const unsigned short* ap = h16 + (size_t)(16 * w + lr) * 3072 + q * 8;
    const unsigned short* bp = Wp + (size_t)(n0 + lr) * 32 + q * 8;
    const size_t bstep = (size_t)NOUT * 32;

    f32x4 acc[4];
#pragma unroll
    for (int i = 0; i < 4; ++i) acc[i] = (f32x4){0.f, 0.f, 0.f, 0.f};

    short8 a  = *(const short8*)ap;
    short8 b0 = *(const short8*)(bp);
    short8 b1 = *(const short8*)(bp + 512);
    short8 b2 = *(const short8*)(bp + 1024);
    short8 b3 = *(const short8*)(bp + 1536);

    for (int kb = 0; kb < 16; ++kb) {
        const size_t nxt = (kb + 1 < 16) ? 1 : 0;
        const unsigned short* apn = ap + nxt * 32;
        const unsigned short* bpn = bp + nxt * bstep;
        short8 an  = *(const short8*)apn;
        short8 bn0 = *(const short8*)(bpn);
        short8 bn1 = *(const short8*)(bpn + 512);
        short8 bn2 = *(const short8*)(bpn + 1024);
        short8 bn3 = *(const short8*)(bpn + 1536);
        acc[0] = __builtin_amdgcn_mfma_f32_16x16x32_bf16(a, b0, acc[0], 0, 0, 0);
        acc[1] = __builtin_amdgcn_mfma_f32_16x16x32_bf16(a, b1, acc[1], 0, 0, 0);
        acc[2] = __builtin_amdgcn_mfma_f32_16x16x32_bf16(a, b2, acc[2], 0, 0, 0);
        acc[3] = __builtin_amdgcn_mfma_f32_16x16x32_bf16(a, b3, acc[3], 0, 0, 0);
        a = an; b0 = bn0; b1 = bn1; b2 = bn2; b3 = bn3;
        ap = apn; bp = bpn;
    }

    const int r0 = q * 4;
#pragma unroll
    for (int cf = 0; cf < 4; ++cf) {
        int col = n0 + cf * 16 + lr;
        float bv = bias[col];
#pragma unroll
        for (int r = 0; r < 4; ++r) {
            int row = 16 * w + r0 + r;
            float v = acc[cf][r] + bv;
            if (col < VOCAB_N) {
                float mk = (t < caplen[row] - 1) ? 1.f : 0.f;
                preds[(size_t)row * ldc + col] = v * mk;
            } else if (col < 10048) {
                // padding, skip
            } else if (col < 12096) {
                gadec[(size_t)row * 2560 + (col - 10048)] = fsigm(v);
            } else {
                gadec[(size_t)row * 2560 + 2048 + (col - 12096)] = v;
            }
        }
    }
}

// ---------------------------------------------------------------------------
// Weight packing: Wp[(kb*Npad + n)*32 + kk] = src[k=kb*32+kk][n], bf16.
// mode 0: single source W1 (K x N1), pad n>=N1 with 0 (Npad >= N1)
// mode 2: k-concat [W1 (K1 x N1) ; W2 ((K-K1) x N1)], Npad = N1
// ---------------------------------------------------------------------------
__global__ void pack_kernel(const float* __restrict__ W1, const float* __restrict__ W2,
                            int N1, int N2, int K1, int Npad, int mode,
                            unsigned short* __restrict__ Wp, int total)
{
    int idx = blockIdx.x * 256 + threadIdx.x;
    if (idx >= total) return;
    int kk = idx & 31;
    int r  = idx >> 5;
    int n  = r % Npad;
    int kb = r / Npad;
    int k  = kb * 32 + kk;
    float v = 0.f;
    if (mode == 0) {
        if (n < N1) v = W1[(size_t)k * N1 + n];
    } else if (mode == 1) {
        v = (n < N1) ? W1[(size_t)k * N1 + n] : W2[(size_t)k * N2 + (n - N1)];
    } else {
        v = (k < K1) ? W1[(size_t)k * N1 + n] : W2[(size_t)(k - K1) * N1 + n];
    }
    Wp[idx] = f2bf(v);
}

// pack [W_fc(10000)+pad48 | W_fbeta(2048) | W_dec_att(512)], K=512, Npad=NOUT
__global__ void pack3_kernel(const float* __restrict__ Wfc,
                             const float* __restrict__ Wfb,
                             const float* __restrict__ Wda,
                             unsigned short* __restrict__ Wp, int total)
{
    int idx = blockIdx.x * 256 + threadIdx.x;
    if (idx >= total) return;
    int kk = idx & 31;
    int r  = idx >> 5;
    int n  = r % NOUT;
    int kb = r / NOUT;
    int k  = kb * 32 + kk;
    float v = 0.f;
    if (n < VOCAB_N)       v = Wfc[(size_t)k * VOCAB_N + n];
    else if (n < 10048)    v = 0.f;
    else if (n < 12096)    v = Wfb[(size_t)k * 2048 + (n - 10048)];
    else                   v = Wda[(size_t)k * 512 + (n - 12096)];
    Wp[idx] = f2bf(v);
}

__global__ void cast_kernel(const float* __restrict__ src,
                            unsigned short* __restrict__ dst, int n)
{
    int i = (blockIdx.x * 256 + threadIdx.x) * 4;
    if (i >= n) return;
    float4 v = *(const float4*)(src + i);
    dst[i]     = f2bf(v.x);
    dst[i + 1] = f2bf(v.y);
    dst[i + 2] = f2bf(v.z);
    dst[i + 3] = f2bf(v.w);
}

// bcat2[NOUT] = [b_fc | 0*48 | b_fbeta | b_dec_att]; bsum[2048] = b_ih + b_hh
__global__ void bias_prep(const float* __restrict__ bfc, const float* __restrict__ bfb,
                          const float* __restrict__ bda, const float* __restrict__ bih,
                          const float* __restrict__ bhh,
                          float* __restrict__ bcat2, float* __restrict__ bsum)
{
    int i = blockIdx.x * 256 + threadIdx.x;
    if (i < VOCAB_N) bcat2[i] = bfc[i];
    else if (i < 10048) bcat2[i] = 0.f;
    else if (i < 12096) bcat2[i] = bfb[i - 10048];
    else if (i < NOUT) bcat2[i] = bda[i - 12096];
    else if (i < NOUT + 2048) { int j = i - NOUT; bsum[j] = bih[j] + bhh[j]; }
}

__global__ void mean_kernel(const float* __restrict__ enc, float* __restrict__ me)
{
    int d = blockIdx.x * 256 + threadIdx.x;
    int b = blockIdx.y;
    const float* p = enc + (size_t)b * NPIX * ENCD + d;
    float s = 0.0f;
    for (int q = 0; q < NPIX; ++q) s += p[(size_t)q * ENCD];
    me[b * ENCD + d] = s * (1.0f / 196.0f);
}

// h0 (bf16 into xcat h-region) + c0 (fp32)
__global__ void inithc_kernel(const float* __restrict__ me,
                              const float* __restrict__ Wh, const float* __restrict__ bh,
                              const float* __restrict__ Wc, const float* __restrict__ bc,
                              unsigned short* __restrict__ xcat, float* __restrict__ c)
{
    int idx = blockIdx.x * 256 + threadIdx.x;  // 0..32767
    int b = idx >> 9, j = idx & 511;
    const float* m = me + b * ENCD;
    float sh = bh[j], sc = bc[j];
    for (int k = 0; k < ENCD; ++k) {
        float mv = m[k];
        sh += mv * Wh[(size_t)k * DECD + j];
        sc += mv * Wc[(size_t)k * DECD + j];
    }
    xcat[(size_t)b * 3072 + 2560 + j] = f2bf(sh);
    c[idx] = sc;
}

__global__ void copy_misc(const int* __restrict__ caps, const int* __restrict__ lens,
                          float* __restrict__ out)
{
    int i = blockIdx.x * 256 + threadIdx.x;
    if (i < CAPS_SZ) out[PRED_SZ + i] = (float)caps[i];
    else if (i < CAPS_SZ + LENS_SZ) out[PRED_SZ + i] = (float)(lens[i - CAPS_SZ] - 1);
}

// ---------------------------------------------------------------------------
// Fused attention + awe + xcat build. One 512-thread block per batch row.
// Phase 1: e[p] = tanh(att_enc16[b,p,:] + adec[b,:]) @ Wf + bf   (8 waves)
// Phase 2: alpha = softmax(e) in LDS; masked alpha -> alphas_out
// Phase 3: awe[d] = sum_p alpha[p]*enc16[b,p,d]; xcat = [emb | gate*awe | h]
// ---------------------------------------------------------------------------
__global__ __launch_bounds__(512) void attawe_kernel(
    const float* __restrict__ gadec,
    const unsigned short* __restrict__ attenc16,
    const unsigned short* __restrict__ enc16,
    const float* __restrict__ Wf, const float* __restrict__ bf_,
    const float* __restrict__ emb, const int* __restrict__ caps,
    const int* __restrict__ caplen, int t,
    unsigned short* __restrict__ xcat,
    float* __restrict__ alphas_out)
{
    int b = blockIdx.x;
    int tid = threadIdx.x;
    int lane = tid & 63, wid = tid >> 6;
    __shared__ float av[512];
    __shared__ float wv[512];
    __shared__ float es[NPIX];
    __shared__ float alpha_s[NPIX];
    __shared__ float r8[8];
    __shared__ float smax, ssum;

    av[tid] = gadec[(size_t)b * 2560 + 2048 + tid];
    wv[tid] = Wf[tid];
    __syncthreads();

    float mya[8], myw[8];
#pragma unroll
    for (int i = 0; i < 8; ++i) {
        mya[i] = av[lane * 8 + i];
        myw[i] = wv[lane * 8 + i];
    }

    float bf0 = bf_[0];
    for (int p = wid; p < NPIX; p += 8) {
        const unsigned short* ae = attenc16 + ((size_t)(b * NPIX + p)) * 512 + lane * 8;
        short8 e8 = *(const short8*)ae;
        float s = 0.f;
#pragma unroll
        for (int i = 0; i < 8; ++i)
            s += ftanh(bf2f((unsigned short)e8[i]) + mya[i]) * myw[i];
        for (int off = 32; off; off >>= 1) s += __shfl_down(s, off);
        if (lane == 0) es[p] = s + bf0;
    }
    __syncthreads();

    float v = (tid < NPIX) ? es[tid] : -1e30f;
    float m = v;
    for (int off = 32; off; off >>= 1) m = fmaxf(m, __shfl_down(m, off));
    if (lane == 0) r8[wid] = m;
    __syncthreads();
    if (tid == 0) {
        float mm = r8[0];
#pragma unroll
        for (int i = 1; i < 8; ++i) mm = fmaxf(mm, r8[i]);
        smax = mm;
    }
    __syncthreads();

    float ev = (tid < NPIX) ? __expf(v - smax) : 0.0f;
    float s = ev;
    for (int off = 32; off; off >>= 1) s += __shfl_down(s, off);
    if (lane == 0) r8[wid] = s;
    __syncthreads();
    if (tid == 0) {
        float ss = 0.f;
#pragma unroll
        for (int i = 0; i < 8; ++i) ss += r8[i];
        ssum = ss;
    }
    __syncthreads();

    float mk = (t < caplen[b] - 1) ? 1.0f : 0.0f;
    if (tid < NPIX) {
        float a = ev / ssum;
        alpha_s[tid] = a;
        alphas_out[((size_t)b * TT + t) * NPIX + tid] = a * mk;
    }
    __syncthreads();

    // awe: 4 d's per thread (512*4 = 2048)
    int d0 = tid * 4;
    const unsigned short* e = enc16 + (size_t)b * NPIX * ENCD + d0;
    float s0 = 0.f, s1 = 0.f, s2 = 0.f, s3 = 0.f;
    for (int p = 0; p < NPIX; ++p) {
        short4v v4 = *(const short4v*)(e + (size_t)p * ENCD);
        float a = alpha_s[p];
        s0 += a * bf2f((unsigned short)v4[0]);
        s1 += a * bf2f((unsigned short)v4[1]);
        s2 += a * bf2f((unsigned short)v4[2]);
        s3 += a * bf2f((unsigned short)v4[3]);
    }
    unsigned short* xr = xcat + (size_t)b * 3072;
    const float* gt = gadec + (size_t)b * 2560 + d0;
    xr[512 + d0 + 0] = f2bf(s0 * gt[0]);
    xr[512 + d0 + 1] = f2bf(s1 * gt[1]);
    xr[512 + d0 + 2] = f2bf(s2 * gt[2]);
    xr[512 + d0 + 3] = f2bf(s3 * gt[3]);

    int wword = caps[b * MAXLEN + t];
    xr[tid] = f2bf(emb[(size_t)wword * 512 + tid]);
}

// LSTM: reduce 8 K-slice partials + bias, gate math, masked c/h update.
__global__ __launch_bounds__(256) void lstm_kernel(
    const float* __restrict__ gparts, const float* __restrict__ bsum,
    const int* __restrict__ caplen, int t,
    float* __restrict__ c, unsigned short* __restrict__ xcat)
{
    int idx = blockIdx.x * 256 + threadIdx.x;  // 0..32767
    int b = idx >> 9, j = idx & 511;
    const float* g = gparts + (size_t)b * 2048;
    float gi = bsum[j],        gf = bsum[512 + j];
    float gg = bsum[1024 + j], go = bsum[1536 + j];
#pragma unroll
    for (int s = 0; s < 8; ++s) {
        const float* p = g + (size_t)s * BB * 2048;
        gi += p[j]; gf += p[512 + j]; gg += p[1024 + j]; go += p[1536 + j];
    }
    float cn = fsigm(gf) * c[idx] + fsigm(gi) * ftanh(gg);
    float hn = fsigm(go) * ftanh(cn);
    if (t < caplen[b] - 1) {
        c[idx] = cn;
        xcat[(size_t)b * 3072 + 2560 + j] = f2bf(hn);
    }
}

// ---------------------------------------------------------------------------
extern "C" void kernel_launch(void* const* d_in, const int* in_sizes, int n_in,
                              void* d_out, int out_size, void* d_ws, size_t ws_size,
                              hipStream_t stream)
{
    (void)in_sizes; (void)n_in; (void)out_size; (void)ws_size;
    const float* enc        = (const float*)d_in[0];
    const int*   caps       = (const int*)d_in[1];
    const int*   lens       = (const int*)d_in[2];
    const float* emb        = (const float*)d_in[3];
    const float* W_enc_att  = (const float*)d_in[4];
    const float* b_enc_att  = (const float*)d_in[5];
    const float* W_dec_att  = (const float*)d_in[6];
    const float* b_dec_att  = (const float*)d_in[7];
    const float* W_full_att = (const float*)d_in[8];
    const float* b_full_att = (const float*)d_in[9];
    const float* W_init_h   = (const float*)d_in[10];
    const float* b_init_h   = (const float*)d_in[11];
    const float* W_init_c   = (const float*)d_in[12];
    const float* b_init_c   = (const float*)d_in[13];
    const float* W_fbeta    = (const float*)d_in[14];
    const float* b_fbeta    = (const float*)d_in[15];
    const float* W_ih       = (const float*)d_in[16];
    const float* W_hh       = (const float*)d_in[17];
    const float* b_ih       = (const float*)d_in[18];
    const float* b_hh       = (const float*)d_in[19];
    const float* W_fc       = (const float*)d_in[20];
    const float* b_fc       = (const float*)d_in[21];
    float* out = (float*)d_out;

    // ---- workspace carve-up (16B aligned chunks) ----
    char* p = (char*)d_ws;
    unsigned short* enc16   = (unsigned short*)p; p += (size_t)BB * NPIX * ENCD * 2;   // 51.4MB
    unsigned short* attenc16= (unsigned short*)p; p += (size_t)BB * NPIX * 512 * 2;    // 12.8MB
    unsigned short* WpL     = (unsigned short*)p; p += (size_t)96 * 2048 * 32 * 2;     // 12.6MB gates K=3072 Npad=2048
    unsigned short* WpO     = (unsigned short*)p; p += (size_t)16 * NOUT * 32 * 2;     // 12.9MB fc|fbeta|dec_att K=512
    unsigned short* WpE     = (unsigned short*)p; p += (size_t)64 * 512 * 32 * 2;      // 2.1MB  enc_att K=2048 Npad=512
    unsigned short* xcat    = (unsigned short*)p; p += (size_t)BB * 3072 * 2;          // 384KB
    float* gadec  = (float*)p; p += (size_t)BB * 2560 * 4;                             // 640KB
    float* gparts = (float*)p; p += (size_t)8 * BB * 2048 * 4;                         // 4MB
    float* c      = (float*)p; p += (size_t)BB * 512 * 4;                              // 128KB
    float* me     = (float*)p; p += (size_t)BB * ENCD * 4;                             // 512KB
    float* bcat2  = (float*)p; p += NOUT * 4;
    float* bsum   = (float*)p; p += 2048 * 4;

    // ---- setup ----
    {
        int n = BB * NPIX * ENCD;
        cast_kernel<<<(n / 4 + 255) / 256, 256, 0, stream>>>(enc, enc16, n);
    }
    { int tot = 96 * 2048 * 32;
      pack_kernel<<<(tot + 255) / 256, 256, 0, stream>>>(W_ih, W_hh, 2048, 2048, 2560, 2048, 2, WpL, tot); }
    { int tot = 16 * NOUT * 32;
      pack3_kernel<<<(tot + 255) / 256, 256, 0, stream>>>(W_fc, W_fbeta, W_dec_att, WpO, tot); }
    { int tot = 64 * 512 * 32;
      pack_kernel<<<(tot + 255) / 256, 256, 0, stream>>>(W_enc_att, nullptr, 512, 0, 0, 512, 0, WpE, tot); }
    bias_prep<<<(NOUT + 2048 + 255) / 256, 256, 0, stream>>>(b_fc, b_fbeta, b_dec_att, b_ih, b_hh, bcat2, bsum);
    mean_kernel<<<dim3(8, 64), 256, 0, stream>>>(enc, me);
    inithc_kernel<<<128, 256, 0, stream>>>(me, W_init_h, b_init_h, W_init_c, b_init_c, xcat, c);
    // att_enc16 = enc16 @ W_enc_att + b  (bf16 out), M=12544
    gemm_mfma<<<dim3(8, 196, 1), 256, 0, stream>>>(
        enc16, ENCD, WpE, 512, 64, 0, nullptr, attenc16, 512,
        b_enc_att, 512, 0, nullptr, 0);
    copy_misc<<<14, 256, 0, stream>>>(caps, lens, out);

    const unsigned short* h16 = xcat + 2560;  // lda = 3072

    // gadec(0) = [sigmoid(h0@Wfbeta+b) | h0@Wd+bd] via tail 40 blocks of outgemm
    outgemm_kernel<<<40, 256, 0, stream>>>(
        h16, WpO, bcat2, lens, 0, out, (long)TT * VOCAB_N, gadec, 157);

    // ---- decode loop: 4 kernels/step ----
    for (int t = 0; t < TT; ++t) {
        attawe_kernel<<<64, 512, 0, stream>>>(
            gadec, attenc16, enc16, W_full_att, b_full_att,
            emb, caps, lens, t, xcat, out + ALPHAS_OFF);
        // gates partials: 8 K-slices of K=3072
        gemm_mfma<<<dim3(32, 1, 8), 256, 0, stream>>>(
            xcat, 3072, WpL, 2048, 12, (long)BB * 2048, gparts, nullptr, 2048,
            nullptr, 2048, 0, nullptr, 0);
        lstm_kernel<<<128, 256, 0, stream>>>(gparts, bsum, lens, t, c, xcat);
        // [preds(t) | gadec(t+1)] = h_{t+1} @ [W_fc | W_fbeta | W_dec_att]
        outgemm_kernel<<<197, 256, 0, stream>>>(
            h16, WpO, bcat2, lens, t, out + (size_t)t * VOCAB_N,
            (long)TT * VOCAB_N, gadec, 0);
    }
}